// Round 2
// baseline (74.407 us; speedup 1.0000x reference)
//
#include <hip/hip_runtime.h>

#define B_   64
#define L_   4096
#define LIM0 4093   // L-3 (tp positions)
#define LIM1 4092   // L-4 (pp positions)

typedef short s16x8 __attribute__((ext_vector_type(8)));
typedef float f32x4 __attribute__((ext_vector_type(4)));

__device__ __forceinline__ unsigned short f2bf(float f) {
    union { float f; unsigned int u; } v; v.f = f;
    unsigned int r = v.u + 0x7FFFu + ((v.u >> 16) & 1u);  // RNE
    return (unsigned short)(r >> 16);
}

struct F3 { float x, y, z; };
__device__ __forceinline__ F3 ld3(const float* p) { return F3{p[0], p[1], p[2]}; }
__device__ __forceinline__ F3 sub3(F3 a, F3 b) { return F3{a.x-b.x, a.y-b.y, a.z-b.z}; }
__device__ __forceinline__ F3 cross3(F3 a, F3 b) {
    return F3{a.y*b.z - a.z*b.y, a.z*b.x - a.x*b.z, a.x*b.y - a.y*b.x};
}
__device__ __forceinline__ float dot3(F3 a, F3 b) { return a.x*b.x + a.y*b.y + a.z*b.z; }

// sin/cos of dihedral defined by 4 points (matches reference arctan2 formulation)
__device__ __forceinline__ void torsion(F3 a, F3 b, F3 c, F3 d, float& sn, float& cs) {
    F3 v1 = sub3(b, a), v2 = sub3(c, b), v3 = sub3(d, c);
    F3 n1 = cross3(v1, v2), n2 = cross3(v2, v3);
    float x = dot3(n1, n2);
    F3 m = cross3(n1, n2);
    float bn = sqrtf(dot3(v2, v2)) + 1e-8f;
    float y = dot3(m, v2) / bn;
    float inv = rsqrtf(x*x + y*y + 1e-30f);
    sn = y * inv; cs = x * inv;
}

// swizzled LDS store: tile is [64 rows][128 cols] of bf16-bits, 16B blocks XOR'd by row&7
__device__ __forceinline__ void xstore(unsigned short* S, int rr, int c, unsigned short v) {
    S[rr*128 + (((c >> 3) ^ (rr & 7)) << 3) + (c & 7)] = v;
}

__global__ __launch_bounds__(256) void ss_mlp(
    const float* __restrict__ R, const int* __restrict__ seq, const float* __restrict__ emb,
    const float* __restrict__ tpW1, const float* __restrict__ tpb1,
    const float* __restrict__ tpW2, const float* __restrict__ tpb2,
    const float* __restrict__ ppW1, const float* __restrict__ ppb1,
    const float* __restrict__ ppW2, const float* __restrict__ ppb2,
    float* __restrict__ ws) {

    __shared__ __align__(16) unsigned short Xs[64*128];
    __shared__ __align__(16) unsigned short H1s[64*128];
    __shared__ unsigned short embs[20*16];

    const int b = blockIdx.y, mode = blockIdx.z;
    const int lim = mode ? LIM1 : LIM0;
    const int IN  = mode ? 68 : 67;
    const float* W1  = mode ? ppW1 : tpW1;
    const float* Bi1 = mode ? ppb1 : tpb1;
    const float* W2  = mode ? ppW2 : tpW2;
    const float* Bi2 = mode ? ppb2 : tpb2;

    const int t = threadIdx.x;
    const int w = t >> 6, l = t & 63, g = l >> 4, ln = l & 15;

    // stage embeddings (bf16) + zero X tile (zeros in pad cols persist forever)
    for (int i = t; i < 320; i += 256) embs[i] = f2bf(emb[i]);
    for (int i = t; i < 1024; i += 256) ((uint4*)Xs)[i] = make_uint4(0u, 0u, 0u, 0u);

    // preload B-fragments (weights) into registers; k-slot convention: k = kk*32 + g*8 + j
    s16x8 bw1[3][2]; s16x8 bw2[4][2]; float bb1[2], bb2[2];
    #pragma unroll
    for (int nt = 0; nt < 2; nt++) {
        const int col = w*32 + nt*16 + ln;
        bb1[nt] = Bi1[col]; bb2[nt] = Bi2[col];
        #pragma unroll
        for (int kk = 0; kk < 3; kk++)
            #pragma unroll
            for (int j = 0; j < 8; j++) {
                int k = kk*32 + g*8 + j;
                bw1[kk][nt][j] = (k < IN) ? (short)f2bf(W1[k*128 + col]) : (short)0;
            }
        #pragma unroll
        for (int kk = 0; kk < 4; kk++)
            #pragma unroll
            for (int j = 0; j < 8; j++) {
                int k = kk*32 + g*8 + j;
                bw2[kk][nt][j] = (short)f2bf(W2[k*128 + col]);
            }
    }

    float s0 = 0.f, s1 = 0.f;
    const int r = t >> 2, sub = t & 3;
    const int cb0 = (mode ? 4 : 3) + sub*16;

    for (int tile = blockIdx.x; tile < 64; tile += 8) {
        const int pos0 = tile << 6;
        __syncthreads();   // prev GEMM1 done reading Xs, prev GEMM2 done reading H1s

        // ---- feature phase: 4 threads per row ----
        {
            const int pos  = pos0 + r;
            const int posc = pos < lim ? pos : lim - 1;   // clamp; masked out of the sum later
            const int aa = seq[b*L_ + posc + sub];
            #pragma unroll
            for (int j = 0; j < 16; j++) xstore(Xs, r, cb0 + j, embs[aa*16 + j]);
            if (sub == 0) {
                const float* Rp = R + ((size_t)(b*L_ + posc))*3;
                F3 p0 = ld3(Rp), p1 = ld3(Rp+3), p2 = ld3(Rp+6), p3 = ld3(Rp+9);
                if (mode == 0) {
                    F3 u1 = sub3(p0, p1), u2 = sub3(p2, p1);
                    F3 cr = cross3(u1, u2);
                    float d = dot3(u1, u2);
                    float ct = d * rsqrtf(d*d + dot3(cr, cr) + 1e-30f);  // cos(theta)
                    float sp, cp; torsion(p0, p1, p2, p3, sp, cp);
                    xstore(Xs, r, 0, f2bf(ct));
                    xstore(Xs, r, 1, f2bf(sp));
                    xstore(Xs, r, 2, f2bf(cp));
                } else {
                    F3 p4 = ld3(Rp+12);
                    float sa, ca, sb, cb;
                    torsion(p0, p1, p2, p3, sa, ca);
                    torsion(p1, p2, p3, p4, sb, cb);
                    xstore(Xs, r, 0, f2bf(sa));
                    xstore(Xs, r, 1, f2bf(ca));
                    xstore(Xs, r, 2, f2bf(sb));
                    xstore(Xs, r, 3, f2bf(cb));
                }
            }
        }
        __syncthreads();

        // ---- GEMM1: H1 = relu(X @ W1 + b1), K = 96 ----
        f32x4 acc0[4], acc1[4];
        #pragma unroll
        for (int m = 0; m < 4; m++) {
            acc0[m] = f32x4{0.f, 0.f, 0.f, 0.f};
            acc1[m] = f32x4{0.f, 0.f, 0.f, 0.f};
        }
        #pragma unroll
        for (int m = 0; m < 4; m++) {
            const int row = m*16 + ln;
            #pragma unroll
            for (int kk = 0; kk < 3; kk++) {
                s16x8 a = *(const s16x8*)&Xs[row*128 + (((kk*4 + g) ^ (row & 7)) << 3)];
                acc0[m] = __builtin_amdgcn_mfma_f32_16x16x32_bf16(a, bw1[kk][0], acc0[m], 0, 0, 0);
                acc1[m] = __builtin_amdgcn_mfma_f32_16x16x32_bf16(a, bw1[kk][1], acc1[m], 0, 0, 0);
            }
        }
        #pragma unroll
        for (int m = 0; m < 4; m++) {
            #pragma unroll
            for (int i = 0; i < 4; i++) {
                const int row = m*16 + g*4 + i;         // C/D: row=(l>>4)*4+i, col=l&15
                const int c0 = w*32 + ln;
                const int c1 = w*32 + 16 + ln;
                xstore(H1s, row, c0, f2bf(fmaxf(acc0[m][i] + bb1[0], 0.f)));
                xstore(H1s, row, c1, f2bf(fmaxf(acc1[m][i] + bb1[1], 0.f)));
            }
        }
        __syncthreads();

        // ---- GEMM2: H2 = relu(H1 @ W2 + b2), K = 128; masked column-sum ----
        f32x4 d0[4], d1[4];
        #pragma unroll
        for (int m = 0; m < 4; m++) {
            d0[m] = f32x4{0.f, 0.f, 0.f, 0.f};
            d1[m] = f32x4{0.f, 0.f, 0.f, 0.f};
        }
        #pragma unroll
        for (int m = 0; m < 4; m++) {
            const int row = m*16 + ln;
            #pragma unroll
            for (int kk = 0; kk < 4; kk++) {
                s16x8 a = *(const s16x8*)&H1s[row*128 + (((kk*4 + g) ^ (row & 7)) << 3)];
                d0[m] = __builtin_amdgcn_mfma_f32_16x16x32_bf16(a, bw2[kk][0], d0[m], 0, 0, 0);
                d1[m] = __builtin_amdgcn_mfma_f32_16x16x32_bf16(a, bw2[kk][1], d1[m], 0, 0, 0);
            }
        }
        #pragma unroll
        for (int m = 0; m < 4; m++) {
            #pragma unroll
            for (int i = 0; i < 4; i++) {
                const int rowg = pos0 + m*16 + g*4 + i;
                if (rowg < lim) {
                    s0 += fmaxf(d0[m][i] + bb2[0], 0.f);
                    s1 += fmaxf(d1[m][i] + bb2[1], 0.f);
                }
            }
        }
    }

    // reduce column partial sums across the 4 row-groups (lanes l, l+16, l+32, l+48 share a col)
    s0 += __shfl_xor(s0, 16, 64); s0 += __shfl_xor(s0, 32, 64);
    s1 += __shfl_xor(s1, 16, 64); s1 += __shfl_xor(s1, 32, 64);
    if (l < 16) {
        float* dst = ws + ((b*2 + mode) << 7) + w*32;
        atomicAdd(dst + l,      s0);
        atomicAdd(dst + 16 + l, s1);
    }
}

__global__ void ss_finish(const float* __restrict__ ws,
                          const float* __restrict__ tpW3, const float* __restrict__ tpb3,
                          const float* __restrict__ ppW3, const float* __restrict__ ppb3,
                          float* __restrict__ out) {
    const int b = blockIdx.x, t = threadIdx.x;   // 128 threads
    float v = ws[(b*2 + 0)*128 + t] * tpW3[t] + ws[(b*2 + 1)*128 + t] * ppW3[t];
    #pragma unroll
    for (int off = 1; off < 64; off <<= 1) v += __shfl_xor(v, off, 64);
    __shared__ float ps[2];
    if ((t & 63) == 0) ps[t >> 6] = v;
    __syncthreads();
    if (t == 0) out[b] = ps[0] + ps[1] + 4093.f * tpb3[0] + 4092.f * ppb3[0];
}

extern "C" void kernel_launch(void* const* d_in, const int* in_sizes, int n_in,
                              void* d_out, int out_size, void* d_ws, size_t ws_size,
                              hipStream_t stream) {
    (void)in_sizes; (void)n_in; (void)out_size; (void)ws_size;
    const float* R    = (const float*)d_in[0];
    const int*   seq  = (const int*)d_in[1];
    const float* emb  = (const float*)d_in[2];
    const float* tpW1 = (const float*)d_in[3];
    const float* tpb1 = (const float*)d_in[4];
    const float* tpW2 = (const float*)d_in[5];
    const float* tpb2 = (const float*)d_in[6];
    const float* tpW3 = (const float*)d_in[7];
    const float* tpb3 = (const float*)d_in[8];
    const float* ppW1 = (const float*)d_in[9];
    const float* ppb1 = (const float*)d_in[10];
    const float* ppW2 = (const float*)d_in[11];
    const float* ppb2 = (const float*)d_in[12];
    const float* ppW3 = (const float*)d_in[13];
    const float* ppb3 = (const float*)d_in[14];
    float* ws = (float*)d_ws;

    hipMemsetAsync(ws, 0, 64*2*128*sizeof(float), stream);
    ss_mlp<<<dim3(8, 64, 2), 256, 0, stream>>>(R, seq, emb,
                                               tpW1, tpb1, tpW2, tpb2,
                                               ppW1, ppb1, ppW2, ppb2, ws);
    ss_finish<<<64, 128, 0, stream>>>(ws, tpW3, tpb3, ppW3, ppb3, (float*)d_out);
}

// Round 3
// 59.450 us; speedup vs baseline: 1.2516x; 1.2516x over previous
//
#include <hip/hip_runtime.h>

#define L_   4096
#define LIM0 4093   // L-3 (tp positions)
#define LIM1 4092   // L-4 (pp positions)

typedef short s16x8 __attribute__((ext_vector_type(8)));
typedef float f32x4 __attribute__((ext_vector_type(4)));

__device__ __forceinline__ unsigned short f2bf(float f) {
    union { float f; unsigned int u; } v; v.f = f;
    unsigned int r = v.u + 0x7FFFu + ((v.u >> 16) & 1u);  // RNE
    return (unsigned short)(r >> 16);
}

__device__ __forceinline__ unsigned int cvt_pk_bf16(float lo, float hi) {
    unsigned int r;
    asm("v_cvt_pk_bf16_f32 %0, %1, %2" : "=v"(r) : "v"(lo), "v"(hi));
    return r;
}

struct F3 { float x, y, z; };
__device__ __forceinline__ F3 ld3(const float* p) { return F3{p[0], p[1], p[2]}; }
__device__ __forceinline__ F3 sub3(F3 a, F3 b) { return F3{a.x-b.x, a.y-b.y, a.z-b.z}; }
__device__ __forceinline__ F3 cross3(F3 a, F3 b) {
    return F3{a.y*b.z - a.z*b.y, a.z*b.x - a.x*b.z, a.x*b.y - a.y*b.x};
}
__device__ __forceinline__ float dot3(F3 a, F3 b) { return a.x*b.x + a.y*b.y + a.z*b.z; }

__device__ __forceinline__ void torsion(F3 a, F3 b, F3 c, F3 d, float& sn, float& cs) {
    F3 v1 = sub3(b, a), v2 = sub3(c, b), v3 = sub3(d, c);
    F3 n1 = cross3(v1, v2), n2 = cross3(v2, v3);
    float x = dot3(n1, n2);
    F3 m = cross3(n1, n2);
    float bn = sqrtf(dot3(v2, v2)) + 1e-8f;
    float y = dot3(m, v2) / bn;
    float inv = rsqrtf(x*x + y*y + 1e-30f);
    sn = y * inv; cs = x * inv;
}

// scalar swizzled store (angle features only): tile [64][128] bf16, 16B blocks XOR'd by row&7
__device__ __forceinline__ void xstore(unsigned short* S, int rr, int c, unsigned short v) {
    S[rr*128 + (((c >> 3) ^ (rr & 7)) << 3) + (c & 7)] = v;
}

__global__ __launch_bounds__(256) void ss_mlp(
    const float* __restrict__ R, const int* __restrict__ seq, const float* __restrict__ emb,
    const float* __restrict__ tpW1, const float* __restrict__ tpb1,
    const float* __restrict__ tpW2, const float* __restrict__ tpb2,
    const float* __restrict__ ppW1, const float* __restrict__ ppb1,
    const float* __restrict__ ppW2, const float* __restrict__ ppb2,
    float* __restrict__ ws) {

    __shared__ __align__(16) unsigned short Xs[64*128];   // [pos][k]: 0..63 ctx, 64.. angles, rest 0
    __shared__ __align__(16) unsigned short H1s[64*128];  // [pos][hidden]
    __shared__ uint4 embs4[40];                           // [aa][half]: 8 packed bf16 each

    const int b = blockIdx.y, mode = blockIdx.z;
    const int lim  = mode ? LIM1 : LIM0;
    const int nang = mode ? 4 : 3;
    const float* W1  = mode ? ppW1 : tpW1;
    const float* Bi1 = mode ? ppb1 : tpb1;
    const float* W2  = mode ? ppW2 : tpW2;
    const float* Bi2 = mode ? ppb2 : tpb2;

    const int t = threadIdx.x;
    const int w = t >> 6, l = t & 63, g = l >> 4, ln = l & 15;
    const int lw = ln & 7;

    // pack embeddings to bf16 uint4 pairs
    if (t < 40) {
        const float* ep = emb + (t >> 1)*16 + (t & 1)*8;
        embs4[t] = make_uint4(cvt_pk_bf16(ep[0], ep[1]), cvt_pk_bf16(ep[2], ep[3]),
                              cvt_pk_bf16(ep[4], ep[5]), cvt_pk_bf16(ep[6], ep[7]));
    }
    // zero X tile once (pad cols stay zero forever)
    for (int i = t; i < 1024; i += 256) ((uint4*)Xs)[i] = make_uint4(0u, 0u, 0u, 0u);

    // A-operand weight fragments: A1 = W1^T (row=hidden, k=input-permuted), A2 = W2^T
    // A frag layout: lane holds A[row = base + ln][k = kk*32 + g*8 + j]
    s16x8 a1f[2][3]; s16x8 a2f[2][4];
    float bb1[2][4], bb2[2][4];
    #pragma unroll
    for (int mt = 0; mt < 2; mt++) {
        const int hc = w*32 + mt*16 + ln;
        #pragma unroll
        for (int kk = 0; kk < 3; kk++)
            #pragma unroll
            for (int j = 0; j < 8; j++) {
                int c = kk*32 + g*8 + j;
                int kp = (c < 64) ? c + (mode ? 4 : 3) : ((c - 64 < nang) ? c - 64 : -1);
                a1f[mt][kk][j] = (kp >= 0) ? (short)f2bf(W1[kp*128 + hc]) : (short)0;
            }
        #pragma unroll
        for (int kk = 0; kk < 4; kk++)
            #pragma unroll
            for (int j = 0; j < 8; j++)
                a2f[mt][kk][j] = (short)f2bf(W2[(kk*32 + g*8 + j)*128 + hc]);
        #pragma unroll
        for (int i = 0; i < 4; i++) {
            bb1[mt][i] = Bi1[w*32 + mt*16 + g*4 + i];
            bb2[mt][i] = Bi2[w*32 + mt*16 + g*4 + i];
        }
    }

    float s[2][4] = {{0.f,0.f,0.f,0.f},{0.f,0.f,0.f,0.f}};
    const int r = t >> 2, sub = t & 3;

    for (int tile = blockIdx.x; tile < 64; tile += 8) {
        const int pos0 = tile << 6;
        __syncthreads();   // all reads of Xs/H1s from previous tile complete

        // ---- feature phase: 4 threads per position row ----
        {
            const int pos  = pos0 + r;
            const int posc = pos < lim ? pos : lim - 1;   // clamp; masked later
            const int aa = seq[b*L_ + posc + sub];
            const int rw = r & 7;
            uint4 e0 = embs4[aa*2], e1 = embs4[aa*2 + 1];
            *(uint4*)(Xs + r*128 + ((( sub*2     ) ^ rw) << 3)) = e0;
            *(uint4*)(Xs + r*128 + ((( sub*2 + 1 ) ^ rw) << 3)) = e1;
            if (sub == 0) {
                const float* Rp = R + ((size_t)(b*L_ + posc))*3;
                F3 p0 = ld3(Rp), p1 = ld3(Rp+3), p2 = ld3(Rp+6), p3 = ld3(Rp+9);
                if (mode == 0) {
                    F3 u1 = sub3(p0, p1), u2 = sub3(p2, p1);
                    F3 cr = cross3(u1, u2);
                    float d = dot3(u1, u2);
                    float ct = d * rsqrtf(d*d + dot3(cr, cr) + 1e-30f);
                    float sp, cp; torsion(p0, p1, p2, p3, sp, cp);
                    xstore(Xs, r, 64, f2bf(ct));
                    xstore(Xs, r, 65, f2bf(sp));
                    xstore(Xs, r, 66, f2bf(cp));
                } else {
                    F3 p4 = ld3(Rp+12);
                    float sa, ca, sb, cb;
                    torsion(p0, p1, p2, p3, sa, ca);
                    torsion(p1, p2, p3, p4, sb, cb);
                    xstore(Xs, r, 64, f2bf(sa));
                    xstore(Xs, r, 65, f2bf(ca));
                    xstore(Xs, r, 66, f2bf(sb));
                    xstore(Xs, r, 67, f2bf(cb));
                }
            }
        }
        __syncthreads();

        // ---- GEMM1 (swapped): D1 = W1^T · X^T ; h1 = relu(D1 + b1) -> H1s[pos][hidden] ----
        #pragma unroll
        for (int pt = 0; pt < 4; pt++) {
            const int row = pt*16 + ln;
            const unsigned short* base = Xs + row*128;
            f32x4 c0 = {0.f,0.f,0.f,0.f}, c1 = {0.f,0.f,0.f,0.f};
            #pragma unroll
            for (int kk = 0; kk < 3; kk++) {
                s16x8 bf = *(const s16x8*)(base + (((kk*4 + g) ^ lw) << 3));
                c0 = __builtin_amdgcn_mfma_f32_16x16x32_bf16(a1f[0][kk], bf, c0, 0, 0, 0);
                c1 = __builtin_amdgcn_mfma_f32_16x16x32_bf16(a1f[1][kk], bf, c1, 0, 0, 0);
            }
            unsigned short* hb = H1s + row*128;
            {
                uint2 u;
                u.x = cvt_pk_bf16(fmaxf(c0[0] + bb1[0][0], 0.f), fmaxf(c0[1] + bb1[0][1], 0.f));
                u.y = cvt_pk_bf16(fmaxf(c0[2] + bb1[0][2], 0.f), fmaxf(c0[3] + bb1[0][3], 0.f));
                *(uint2*)(hb + ((((w*4) + (g>>1)) ^ lw) << 3) + (g&1)*4) = u;
            }
            {
                uint2 u;
                u.x = cvt_pk_bf16(fmaxf(c1[0] + bb1[1][0], 0.f), fmaxf(c1[1] + bb1[1][1], 0.f));
                u.y = cvt_pk_bf16(fmaxf(c1[2] + bb1[1][2], 0.f), fmaxf(c1[3] + bb1[1][3], 0.f));
                *(uint2*)(hb + ((((w*4 + 2) + (g>>1)) ^ lw) << 3) + (g&1)*4) = u;
            }
        }
        __syncthreads();

        // ---- GEMM2 (swapped): D2 = W2^T · H1^T ; masked colsum of relu(D2 + b2) ----
        #pragma unroll
        for (int pt = 0; pt < 4; pt++) {
            const int row = pt*16 + ln;
            const unsigned short* base = H1s + row*128;
            f32x4 d0 = {0.f,0.f,0.f,0.f}, d1 = {0.f,0.f,0.f,0.f};
            #pragma unroll
            for (int kk = 0; kk < 4; kk++) {
                s16x8 bf = *(const s16x8*)(base + (((kk*4 + g) ^ lw) << 3));
                d0 = __builtin_amdgcn_mfma_f32_16x16x32_bf16(a2f[0][kk], bf, d0, 0, 0, 0);
                d1 = __builtin_amdgcn_mfma_f32_16x16x32_bf16(a2f[1][kk], bf, d1, 0, 0, 0);
            }
            if (pos0 + row < lim) {
                #pragma unroll
                for (int i = 0; i < 4; i++) {
                    s[0][i] += fmaxf(d0[i] + bb2[0][i], 0.f);
                    s[1][i] += fmaxf(d1[i] + bb2[1][i], 0.f);
                }
            }
        }
    }

    // reduce across the 16 lanes sharing each hidden index, then one atomic per value
    #pragma unroll
    for (int mt = 0; mt < 2; mt++)
        #pragma unroll
        for (int i = 0; i < 4; i++) {
            float v = s[mt][i];
            v += __shfl_xor(v, 1, 64); v += __shfl_xor(v, 2, 64);
            v += __shfl_xor(v, 4, 64); v += __shfl_xor(v, 8, 64);
            if (ln == 0)
                atomicAdd(ws + ((b*2 + mode) << 7) + w*32 + mt*16 + g*4 + i, v);
        }
}

__global__ void ss_finish(const float* __restrict__ ws,
                          const float* __restrict__ tpW3, const float* __restrict__ tpb3,
                          const float* __restrict__ ppW3, const float* __restrict__ ppb3,
                          float* __restrict__ out) {
    const int b = blockIdx.x, t = threadIdx.x;   // 128 threads
    float v = ws[(b*2 + 0)*128 + t] * tpW3[t] + ws[(b*2 + 1)*128 + t] * ppW3[t];
    #pragma unroll
    for (int off = 1; off < 64; off <<= 1) v += __shfl_xor(v, off, 64);
    __shared__ float ps[2];
    if ((t & 63) == 0) ps[t >> 6] = v;
    __syncthreads();
    if (t == 0) out[b] = ps[0] + ps[1] + 4093.f * tpb3[0] + 4092.f * ppb3[0];
}

extern "C" void kernel_launch(void* const* d_in, const int* in_sizes, int n_in,
                              void* d_out, int out_size, void* d_ws, size_t ws_size,
                              hipStream_t stream) {
    (void)in_sizes; (void)n_in; (void)out_size; (void)ws_size;
    const float* R    = (const float*)d_in[0];
    const int*   seq  = (const int*)d_in[1];
    const float* emb  = (const float*)d_in[2];
    const float* tpW1 = (const float*)d_in[3];
    const float* tpb1 = (const float*)d_in[4];
    const float* tpW2 = (const float*)d_in[5];
    const float* tpb2 = (const float*)d_in[6];
    const float* tpW3 = (const float*)d_in[7];
    const float* tpb3 = (const float*)d_in[8];
    const float* ppW1 = (const float*)d_in[9];
    const float* ppb1 = (const float*)d_in[10];
    const float* ppW2 = (const float*)d_in[11];
    const float* ppb2 = (const float*)d_in[12];
    const float* ppW3 = (const float*)d_in[13];
    const float* ppb3 = (const float*)d_in[14];
    float* ws = (float*)d_ws;

    hipMemsetAsync(ws, 0, 64*2*128*sizeof(float), stream);
    ss_mlp<<<dim3(8, 64, 2), 256, 0, stream>>>(R, seq, emb,
                                               tpW1, tpb1, tpW2, tpb2,
                                               ppW1, ppb1, ppW2, ppb2, ws);
    ss_finish<<<64, 128, 0, stream>>>(ws, tpW3, tpb3, ppW3, ppb3, (float*)d_out);
}

// Round 6
// 51.183 us; speedup vs baseline: 1.4537x; 1.1615x over previous
//
#include <hip/hip_runtime.h>

#define L_   4096
#define LIM0 4093   // L-3 (tp positions)
#define LIM1 4092   // L-4 (pp positions)

typedef short s16x8 __attribute__((ext_vector_type(8)));
typedef float f32x4 __attribute__((ext_vector_type(4)));

__device__ __forceinline__ unsigned short f2bf(float f) {
    union { float f; unsigned int u; } v; v.f = f;
    unsigned int r = v.u + 0x7FFFu + ((v.u >> 16) & 1u);  // RNE
    return (unsigned short)(r >> 16);
}

__device__ __forceinline__ unsigned int cvt_pk_bf16(float lo, float hi) {
    unsigned int r;
    asm("v_cvt_pk_bf16_f32 %0, %1, %2" : "=v"(r) : "v"(lo), "v"(hi));
    return r;
}

struct F3 { float x, y, z; };
__device__ __forceinline__ F3 ld3(const float* p) { return F3{p[0], p[1], p[2]}; }
__device__ __forceinline__ F3 sub3(F3 a, F3 b) { return F3{a.x-b.x, a.y-b.y, a.z-b.z}; }
__device__ __forceinline__ F3 cross3(F3 a, F3 b) {
    return F3{a.y*b.z - a.z*b.y, a.z*b.x - a.x*b.z, a.x*b.y - a.y*b.x};
}
__device__ __forceinline__ float dot3(F3 a, F3 b) { return a.x*b.x + a.y*b.y + a.z*b.z; }

__device__ __forceinline__ void torsion(F3 a, F3 b, F3 c, F3 d, float& sn, float& cs) {
    F3 v1 = sub3(b, a), v2 = sub3(c, b), v3 = sub3(d, c);
    F3 n1 = cross3(v1, v2), n2 = cross3(v2, v3);
    float x = dot3(n1, n2);
    F3 m = cross3(n1, n2);
    float bn = sqrtf(dot3(v2, v2)) + 1e-8f;
    float y = dot3(m, v2) / bn;
    float inv = rsqrtf(x*x + y*y + 1e-30f);
    sn = y * inv; cs = x * inv;
}

// scalar swizzled LDS store: tile [64][256B], 16B blocks XOR'd by row&7 (within 8-block group)
__device__ __forceinline__ void xstore(unsigned short* S, int rr, int c, unsigned short v) {
    S[rr*128 + (((c >> 3) ^ (rr & 7)) << 3) + (c & 7)] = v;
}

// ---- pre-kernel: per-position angle features, fully lane-parallel, no divergence ----
// feat[b*L+p] = {pk(cos_theta(p), 1.0), pk(sin_phi(p), cos_phi(p))}  (bf16 packed)
__global__ __launch_bounds__(256) void ss_feat(const float* __restrict__ R,
                                               uint2* __restrict__ feat) {
    const int p = blockIdx.x * 256 + threadIdx.x;
    const int b = blockIdx.y;
    if (p >= LIM0) return;
    const float* Rp = R + ((size_t)(b * L_ + p)) * 3;
    F3 p0 = ld3(Rp), p1 = ld3(Rp + 3), p2 = ld3(Rp + 6), p3 = ld3(Rp + 9);
    F3 u1 = sub3(p0, p1), u2 = sub3(p2, p1);
    F3 cr = cross3(u1, u2);
    float d = dot3(u1, u2);
    float ct = d * rsqrtf(d * d + dot3(cr, cr) + 1e-30f);   // cos(theta at p+1)
    float sp, cp; torsion(p0, p1, p2, p3, sp, cp);
    feat[(size_t)b * L_ + p] = make_uint2(cvt_pk_bf16(ct, 1.0f), cvt_pk_bf16(sp, cp));
}

__global__ __launch_bounds__(256) void ss_mlp(
    const int* __restrict__ seq, const uint2* __restrict__ feat, const float* __restrict__ emb,
    const float* __restrict__ tpW1, const float* __restrict__ tpb1,
    const float* __restrict__ tpW2, const float* __restrict__ tpb2,
    const float* __restrict__ ppW1, const float* __restrict__ ppb1,
    const float* __restrict__ ppW2, const float* __restrict__ ppb2,
    float* __restrict__ ws) {

    __shared__ __align__(16) unsigned short Xs[64*128];   // [pos][k]: 0..63 ctx, 64..67 feat, 68 one
    __shared__ __align__(16) unsigned short H1s[64*128];  // [pos][hidden]
    __shared__ uint4 embs4[40];

    const int b = blockIdx.y, mode = blockIdx.z;
    const int lim  = mode ? LIM1 : LIM0;
    const float* W1  = mode ? ppW1 : tpW1;
    const float* Bi1 = mode ? ppb1 : tpb1;
    const float* W2  = mode ? ppW2 : tpW2;
    const float* Bi2 = mode ? ppb2 : tpb2;

    const int t = threadIdx.x;
    const int w = t >> 6, l = t & 63, g = l >> 4, ln = l & 15;
    const int lw = ln & 7;
    const int r = t >> 2, sub = t & 3;
    const int rw = r & 7;

    // stage tile0's global data immediately (latency hidden under setup below)
    int aa_; uint2 fv_, fv2_;
    {
        const int posc = min(blockIdx.x * 64 + r, lim - 1);
        aa_ = seq[b * L_ + posc + sub];
        if (sub == 0) {
            fv_ = feat[(size_t)b * L_ + posc];
            if (mode) fv2_ = feat[(size_t)b * L_ + posc + 1];
        }
    }

    // pack embeddings to bf16 + zero X tile
    if (t < 40) {
        const float* ep = emb + (t >> 1) * 16 + (t & 1) * 8;
        embs4[t] = make_uint4(cvt_pk_bf16(ep[0], ep[1]), cvt_pk_bf16(ep[2], ep[3]),
                              cvt_pk_bf16(ep[4], ep[5]), cvt_pk_bf16(ep[6], ep[7]));
    }
    for (int i = t; i < 1024; i += 256) ((uint4*)Xs)[i] = make_uint4(0u, 0u, 0u, 0u);

    // A-operand weight fragments (A1 = W1^T permuted + bias1 folded via the 1.0 column; A2 = W2^T)
    // A frag layout: lane holds A[row = hc][k = kk*32 + g*8 + j]
    s16x8 a1f[2][3]; s16x8 a2f[2][4];
    float bb2[2][4];
    #pragma unroll
    for (int mt = 0; mt < 2; mt++) {
        const int hc = w*32 + mt*16 + ln;
        #pragma unroll
        for (int kk = 0; kk < 3; kk++)
            #pragma unroll
            for (int j = 0; j < 8; j++) {
                const int c = kk*32 + g*8 + j;
                // k-column -> W1 row (or bias / zero-pad)
                int kp;
                if (mode) kp = (c < 64) ? c + 4 : ((c < 68) ? c - 64 : ((c == 68) ? -2 : -1));
                else      kp = (c < 64) ? c + 3 : ((c == 64) ? 0 : ((c == 65) ? -2 :
                               ((c == 66) ? 1 : ((c == 67) ? 2 : -1))));
                float wv = (kp == -1) ? 0.f : ((kp == -2) ? Bi1[hc] : W1[kp*128 + hc]);
                a1f[mt][kk][j] = (short)f2bf(wv);
            }
        #pragma unroll
        for (int kk = 0; kk < 4; kk++)
            #pragma unroll
            for (int j = 0; j < 8; j++)
                a2f[mt][kk][j] = (short)f2bf(W2[(kk*32 + g*8 + j)*128 + hc]);
        #pragma unroll
        for (int i = 0; i < 4; i++) bb2[mt][i] = Bi2[w*32 + mt*16 + g*4 + i];
    }

    __syncthreads();   // embs4 + zeroed Xs visible

    // write tile0 into Xs
    {
        uint4 e0 = embs4[aa_*2], e1 = embs4[aa_*2 + 1];
        *(uint4*)(Xs + r*128 + (((sub*2    ) ^ rw) << 3)) = e0;
        *(uint4*)(Xs + r*128 + (((sub*2 + 1) ^ rw) << 3)) = e1;
        if (sub == 0) {
            uint2 u = mode ? make_uint2(fv_.y, fv2_.y) : fv_;
            *(uint2*)(Xs + r*128 + ((8 ^ rw) << 3)) = u;   // cols 64..67
        }
    }
    if (t < 64) xstore(Xs, t, 68, (unsigned short)0x3F80);  // bias-one col (mode1)
    __syncthreads();

    float s[2][4] = {{0.f,0.f,0.f,0.f},{0.f,0.f,0.f,0.f}};

    for (int tile = blockIdx.x; tile < 64; tile += 8) {
        const int pos0 = tile << 6;
        const bool has_next = (tile + 8) < 64;

        // prefetch next tile's globals (in flight during GEMM1)
        if (has_next) {
            const int posc = min(pos0 + 512 + r, lim - 1);
            aa_ = seq[b * L_ + posc + sub];
            if (sub == 0) {
                fv_ = feat[(size_t)b * L_ + posc];
                if (mode) fv2_ = feat[(size_t)b * L_ + posc + 1];
            }
        }

        // ---- GEMM1: D1 = W1^T · X^T ; h1 = relu(D1) (bias folded) -> H1s[pos][hidden] ----
        #pragma unroll
        for (int pt = 0; pt < 4; pt++) {
            const int row = pt*16 + ln;
            const unsigned short* base = Xs + row*128;
            f32x4 c0 = {0.f,0.f,0.f,0.f}, c1 = {0.f,0.f,0.f,0.f};
            #pragma unroll
            for (int kk = 0; kk < 3; kk++) {
                s16x8 bf = *(const s16x8*)(base + (((kk*4 + g) ^ lw) << 3));
                c0 = __builtin_amdgcn_mfma_f32_16x16x32_bf16(a1f[0][kk], bf, c0, 0, 0, 0);
                c1 = __builtin_amdgcn_mfma_f32_16x16x32_bf16(a1f[1][kk], bf, c1, 0, 0, 0);
            }
            unsigned short* hb = H1s + row*128;
            {
                uint2 u;
                u.x = cvt_pk_bf16(fmaxf(c0[0], 0.f), fmaxf(c0[1], 0.f));
                u.y = cvt_pk_bf16(fmaxf(c0[2], 0.f), fmaxf(c0[3], 0.f));
                *(uint2*)(hb + ((((w*4) + (g>>1)) ^ lw) << 3) + (g&1)*4) = u;
            }
            {
                uint2 u;
                u.x = cvt_pk_bf16(fmaxf(c1[0], 0.f), fmaxf(c1[1], 0.f));
                u.y = cvt_pk_bf16(fmaxf(c1[2], 0.f), fmaxf(c1[3], 0.f));
                *(uint2*)(hb + ((((w*4 + 2) + (g>>1)) ^ lw) << 3) + (g&1)*4) = u;
            }
        }
        __syncthreads();   // B1: Xs reads + H1s writes complete

        // write NEXT tile's Xs (concurrent with GEMM2's H1s reads)
        if (has_next) {
            uint4 e0 = embs4[aa_*2], e1 = embs4[aa_*2 + 1];
            *(uint4*)(Xs + r*128 + (((sub*2    ) ^ rw) << 3)) = e0;
            *(uint4*)(Xs + r*128 + (((sub*2 + 1) ^ rw) << 3)) = e1;
            if (sub == 0) {
                uint2 u = mode ? make_uint2(fv_.y, fv2_.y) : fv_;
                *(uint2*)(Xs + r*128 + ((8 ^ rw) << 3)) = u;
            }
        }

        // ---- GEMM2: D2 = W2^T · H1^T ; masked colsum of relu(D2 + b2) ----
        #pragma unroll
        for (int pt = 0; pt < 4; pt++) {
            const int row = pt*16 + ln;
            const unsigned short* base = H1s + row*128;
            f32x4 d0 = {0.f,0.f,0.f,0.f}, d1 = {0.f,0.f,0.f,0.f};
            #pragma unroll
            for (int kk = 0; kk < 4; kk++) {
                s16x8 bf = *(const s16x8*)(base + (((kk*4 + g) ^ lw) << 3));
                d0 = __builtin_amdgcn_mfma_f32_16x16x32_bf16(a2f[0][kk], bf, d0, 0, 0, 0);
                d1 = __builtin_amdgcn_mfma_f32_16x16x32_bf16(a2f[1][kk], bf, d1, 0, 0, 0);
            }
            if (pos0 + row < lim) {
                #pragma unroll
                for (int i = 0; i < 4; i++) {
                    s[0][i] += fmaxf(d0[i] + bb2[0][i], 0.f);
                    s[1][i] += fmaxf(d1[i] + bb2[1][i], 0.f);
                }
            }
        }
        __syncthreads();   // B2: H1s reads + next-Xs writes complete
    }

    // reduce across the 16 lanes sharing each hidden index, one atomic per value
    #pragma unroll
    for (int mt = 0; mt < 2; mt++)
        #pragma unroll
        for (int i = 0; i < 4; i++) {
            float v = s[mt][i];
            v += __shfl_xor(v, 1, 64); v += __shfl_xor(v, 2, 64);
            v += __shfl_xor(v, 4, 64); v += __shfl_xor(v, 8, 64);
            if (ln == 0)
                atomicAdd(ws + ((b*2 + mode) << 7) + w*32 + mt*16 + g*4 + i, v);
        }
}

__global__ void ss_finish(const float* __restrict__ ws,
                          const float* __restrict__ tpW3, const float* __restrict__ tpb3,
                          const float* __restrict__ ppW3, const float* __restrict__ ppb3,
                          float* __restrict__ out) {
    const int b = blockIdx.x, t = threadIdx.x;   // 128 threads
    float v = ws[(b*2 + 0)*128 + t] * tpW3[t] + ws[(b*2 + 1)*128 + t] * ppW3[t];
    #pragma unroll
    for (int off = 1; off < 64; off <<= 1) v += __shfl_xor(v, off, 64);
    __shared__ float ps[2];
    if ((t & 63) == 0) ps[t >> 6] = v;
    __syncthreads();
    if (t == 0) out[b] = ps[0] + ps[1] + 4093.f * tpb3[0] + 4092.f * ppb3[0];
}

extern "C" void kernel_launch(void* const* d_in, const int* in_sizes, int n_in,
                              void* d_out, int out_size, void* d_ws, size_t ws_size,
                              hipStream_t stream) {
    (void)in_sizes; (void)n_in; (void)out_size; (void)ws_size;
    const float* R    = (const float*)d_in[0];
    const int*   seq  = (const int*)d_in[1];
    const float* emb  = (const float*)d_in[2];
    const float* tpW1 = (const float*)d_in[3];
    const float* tpb1 = (const float*)d_in[4];
    const float* tpW2 = (const float*)d_in[5];
    const float* tpb2 = (const float*)d_in[6];
    const float* tpW3 = (const float*)d_in[7];
    const float* tpb3 = (const float*)d_in[8];
    const float* ppW1 = (const float*)d_in[9];
    const float* ppb1 = (const float*)d_in[10];
    const float* ppW2 = (const float*)d_in[11];
    const float* ppb2 = (const float*)d_in[12];
    const float* ppW3 = (const float*)d_in[13];
    const float* ppb3 = (const float*)d_in[14];
    float* ws   = (float*)d_ws;                                   // [0, 64KB): column sums
    uint2* feat = (uint2*)((char*)d_ws + 65536);                  // [64KB, 64KB+2MB): features

    hipMemsetAsync(ws, 0, 64*2*128*sizeof(float), stream);
    ss_feat<<<dim3(16, 64), 256, 0, stream>>>(R, feat);
    ss_mlp<<<dim3(8, 64, 2), 256, 0, stream>>>(seq, feat, emb,
                                               tpW1, tpb1, tpW2, tpb2,
                                               ppW1, ppb1, ppW2, ppb2, ws);
    ss_finish<<<64, 128, 0, stream>>>(ws, tpW3, tpb3, ppW3, ppb3, (float*)d_out);
}